// Round 21
// baseline (1836.977 us; speedup 1.0000x reference)
//
#include <hip/hip_runtime.h>
#include <hip/hip_bf16.h>
#include <stdint.h>

#define AS1 __attribute__((address_space(1)))
#define AS3 __attribute__((address_space(3)))

using bf16x8 = __attribute__((ext_vector_type(8))) short;
using f32x4  = __attribute__((ext_vector_type(4))) float;

static constexpr int NROWS = 8192;   // N
static constexpr int DM    = 2048;   // d_model
static constexpr int DD    = 16384;  // d_dict
static constexpr int KSEL  = 64;
static constexpr int CCAP  = 768;    // compact pool cap/row
static constexpr int SLOTS = 24;     // LDS pool slots per row per col-block (λ=2.16, P(>24)~1e-17/cell)
static constexpr int SORTN = 256;    // bitonic width (cand mean 84, 19-sigma safe)
#define POOLTHR 1.0f
#define MARGIN  0.03f

using OutT = unsigned short;  // bf16 bit pattern

__device__ __forceinline__ unsigned short f2bf(float f) {
  unsigned u = __float_as_uint(f);
  u += 0x7FFFu + ((u >> 16) & 1u);
  return (unsigned short)(u >> 16);
}
__device__ __forceinline__ void gload16(const void* g, void* l) {
  __builtin_amdgcn_global_load_lds((const AS1 void*)g, (AS3 void*)l, 16, 0, 0);
}

// ---------------- fused init: colsum+accs (block 0) + rowcnt (blocks 1..32)
__global__ void k_init(double* __restrict__ colsum, unsigned* __restrict__ rowcnt) {
  if (blockIdx.x == 0) {
    for (int i = threadIdx.x; i < 2048 + 8; i += 256) colsum[i] = 0.0;
  } else {
    rowcnt[(blockIdx.x - 1) * 256 + threadIdx.x] = 0u;
  }
}

// ---------------- fused conv_x + colstats: one pass over x ----------------
__global__ void k_convx_stats(const float* __restrict__ x, const float* __restrict__ bd,
                              OutT* __restrict__ xb, double* __restrict__ colsum,
                              double* __restrict__ accs) {
  __shared__ double rd[256];
  const int b = blockIdx.x;          // 64 blocks, 128 rows each
  const int c0 = threadIdx.x * 8;
  float4 bv0 = *(const float4*)(bd + c0);
  float4 bv1 = *(const float4*)(bd + c0 + 4);
  float s0=0,s1=0,s2=0,s3=0,s4=0,s5=0,s6=0,s7=0;
  double sq = 0.0;
  for (int r = 0; r < 128; ++r) {
    const size_t base = (size_t)(b * 128 + r) * DM + c0;
    float4 u = *(const float4*)(x + base);
    float4 v = *(const float4*)(x + base + 4);
    s0+=u.x; s1+=u.y; s2+=u.z; s3+=u.w; s4+=v.x; s5+=v.y; s6+=v.z; s7+=v.w;
    sq += (double)u.x*u.x + (double)u.y*u.y + (double)u.z*u.z + (double)u.w*u.w
        + (double)v.x*v.x + (double)v.y*v.y + (double)v.z*v.z + (double)v.w*v.w;
    unsigned o0 = f2bf(u.x - bv0.x), o1 = f2bf(u.y - bv0.y);
    unsigned o2 = f2bf(u.z - bv0.z), o3 = f2bf(u.w - bv0.w);
    unsigned o4 = f2bf(v.x - bv1.x), o5 = f2bf(v.y - bv1.y);
    unsigned o6 = f2bf(v.z - bv1.z), o7 = f2bf(v.w - bv1.w);
    uint4 p;
    p.x = o0 | (o1 << 16); p.y = o2 | (o3 << 16);
    p.z = o4 | (o5 << 16); p.w = o6 | (o7 << 16);
    *(uint4*)(xb + base) = p;
  }
  atomicAdd(&colsum[c0+0], (double)s0); atomicAdd(&colsum[c0+1], (double)s1);
  atomicAdd(&colsum[c0+2], (double)s2); atomicAdd(&colsum[c0+3], (double)s3);
  atomicAdd(&colsum[c0+4], (double)s4); atomicAdd(&colsum[c0+5], (double)s5);
  atomicAdd(&colsum[c0+6], (double)s6); atomicAdd(&colsum[c0+7], (double)s7);
  rd[threadIdx.x] = sq; __syncthreads();
  for (int off = 128; off > 0; off >>= 1) {
    if ((int)threadIdx.x < off) rd[threadIdx.x] += rd[threadIdx.x + off];
    __syncthreads();
  }
  if (threadIdx.x == 0) atomicAdd(&accs[2], rd[0]);
}

__global__ void k_conv_w(const float* __restrict__ src, OutT* __restrict__ dst) {
  size_t i = ((size_t)blockIdx.x * blockDim.x + threadIdx.x) * 8;
  float4 a = *(const float4*)(src + i);
  float4 b = *(const float4*)(src + i + 4);
  unsigned o0 = f2bf(a.x), o1 = f2bf(a.y), o2 = f2bf(a.z), o3 = f2bf(a.w);
  unsigned o4 = f2bf(b.x), o5 = f2bf(b.y), o6 = f2bf(b.z), o7 = f2bf(b.w);
  uint4 p;
  p.x = o0 | (o1 << 16); p.y = o2 | (o3 << 16);
  p.z = o4 | (o5 << 16); p.w = o6 | (o7 << 16);
  *(uint4*)(dst + i) = p;
}

// transpose W_dec (DM x DD, f32) -> wdt (DD x DM, bf16)
__global__ void k_twdec(const float* __restrict__ wd, OutT* __restrict__ wdt) {
  __shared__ float t[32][33];
  const int ct = blockIdx.x;
  const int rt = blockIdx.y;
  const int tid = threadIdx.x;
  const int r  = tid >> 3;
  const int c4 = (tid & 7) * 4;
  float4 v = *(const float4*)(wd + (size_t)(rt * 32 + r) * DD + ct * 32 + c4);
  t[r][c4 + 0] = v.x; t[r][c4 + 1] = v.y; t[r][c4 + 2] = v.z; t[r][c4 + 3] = v.w;
  __syncthreads();
  unsigned a = f2bf(t[c4 + 0][r]), b = f2bf(t[c4 + 1][r]);
  unsigned c = f2bf(t[c4 + 2][r]), d = f2bf(t[c4 + 3][r]);
  uint2 p; p.x = a | (b << 16); p.y = c | (d << 16);
  *(uint2*)(wdt + (size_t)(ct * 32 + r) * DM + rt * 32 + c4) = p;
}

// ---------------- bf16 MFMA GEMM (gload_lds, 16 KB LDS arena) --------------
// XCD-band swizzle + SLOTS=24 arena => 8 blocks/CU (full grid residency).
__global__ __launch_bounds__(256, 2) void k_gemm(
    const OutT* __restrict__ A,
    const OutT* __restrict__ B,
    const float* __restrict__ bias,
    float* __restrict__ h,
    unsigned* __restrict__ poolc,
    unsigned* __restrict__ rowcnt)
{
  __shared__ __align__(16) unsigned smem[4096];   // 16 KB arena
  OutT* As = (OutT*)smem;                          // [0, 8 KB)
  OutT* Bs = (OutT*)smem + 4096;                   // [8 KB, 16 KB)
  unsigned (*lpool)[SLOTS] = (unsigned(*)[SLOTS])smem;   // epilogue reuse
  unsigned* lcnt  = smem + 128 * SLOTS;            // 3072
  unsigned* lbase = smem + 128 * SLOTS + 128;      // 3200

  const int bid = blockIdx.x;
  const int xcd = bid & 7;
  const int idx = bid >> 3;               // 0..1023 within XCD
  const int bn  = xcd * 16 + (idx & 15);  // B band fixed per XCD
  const int bm  = idx >> 4;               // A panels swept 0..63
  const int tid = threadIdx.x;
  const int lane = tid & 63;
  const int wv = tid >> 6;
  const int wm = wv >> 1, wn = wv & 1;

  const int c0 = wv * 2, c1 = wv * 2 + 1;
  const int sr0 = c0 * 16 + (lane >> 2);
  const int sr1 = c1 * 16 + (lane >> 2);
  const int sk  = (lane & 3) * 8;
  const OutT* gA0 = A + (size_t)(bm * 128 + sr0) * DM + sk;
  const OutT* gA1 = A + (size_t)(bm * 128 + sr1) * DM + sk;
  const OutT* gB0 = B + (size_t)(bn * 128 + sr0) * DM + sk;
  const OutT* gB1 = B + (size_t)(bn * 128 + sr1) * DM + sk;
  OutT* lA0 = &As[c0 * 512];
  OutT* lA1 = &As[c1 * 512];
  OutT* lB0 = &Bs[c0 * 512];
  OutT* lB1 = &Bs[c1 * 512];

  const int fr = lane & 15;
  const int kg = (lane >> 4) * 8;

  f32x4 acc[4][4] = {};

  for (int kt = 0; kt < DM / 32; ++kt) {
    gload16(gA0, lA0); gload16(gA1, lA1);
    gload16(gB0, lB0); gload16(gB1, lB1);
    gA0 += 32; gA1 += 32; gB0 += 32; gB1 += 32;
    __syncthreads();
    bf16x8 af[4], bfr[4];
#pragma unroll
    for (int m = 0; m < 4; ++m)
      af[m] = *(const bf16x8*)&As[(wm * 64 + m * 16 + fr) * 32 + kg];
#pragma unroll
    for (int n = 0; n < 4; ++n)
      bfr[n] = *(const bf16x8*)&Bs[(wn * 64 + n * 16 + fr) * 32 + kg];
#pragma unroll
    for (int m = 0; m < 4; ++m)
#pragma unroll
      for (int n = 0; n < 4; ++n)
        acc[m][n] = __builtin_amdgcn_mfma_f32_16x16x32_bf16(af[m], bfr[n], acc[m][n], 0, 0, 0);
    __syncthreads();
  }

  // ---- epilogue: staging dead; arena becomes the candidate pool ----
  if (tid < 128) lcnt[tid] = 0;
  __syncthreads();
  const int r0 = (lane >> 4) * 4;   // C/D: col = lane&15, row = (lane>>4)*4 + reg
#pragma unroll
  for (int n = 0; n < 4; ++n) {
    const int col = bn * 128 + wn * 64 + n * 16 + fr;
    const float bv = bias[col];
#pragma unroll
    for (int m = 0; m < 4; ++m) {
      const int lr = wm * 64 + m * 16 + r0;
#pragma unroll
      for (int r = 0; r < 4; ++r) {
        float v = acc[m][n][r] + bv;
        if (v > POOLTHR) {
          unsigned pos = atomicAdd(&lcnt[lr + r], 1u);
          if (pos < (unsigned)SLOTS)
            lpool[lr + r][pos] = ((unsigned)f2bf(v) << 16) | (unsigned)col;
        }
      }
    }
  }
  __syncthreads();
  if (tid < 128) {
    unsigned c = lcnt[tid]; if (c > (unsigned)SLOTS) c = SLOTS;
    lcnt[tid] = c;
    lbase[tid] = c ? atomicAdd(&rowcnt[bm * 128 + tid], c) : 0u;
  }
  __syncthreads();
  for (int i = tid; i < 128 * SLOTS; i += 256) {
    const int lr = i / SLOTS;
    const int slot = i - lr * SLOTS;
    if (slot < (int)lcnt[lr]) {
      unsigned p = lbase[lr] + (unsigned)slot;
      if (p < (unsigned)CCAP)
        poolc[(size_t)(bm * 128 + lr) * CCAP + p] = lpool[lr][slot];
    }
  }
  const f32x4 z4 = {0.f, 0.f, 0.f, 0.f};
  for (int i = tid; i < 4096; i += 256) {
    const int lr = i >> 5, cc = i & 31;
    __builtin_nontemporal_store(z4,
        (f32x4*)(h + (size_t)(bm * 128 + lr) * DD + bn * 128) + cc);
  }
}

// ---------------- select: pool -> thr -> exact f32 rescore -> bitonic top-64
__global__ __launch_bounds__(256) void k_select(
    unsigned* __restrict__ hbuf,
    const unsigned* __restrict__ poolc,
    const unsigned* __restrict__ rowcnt,
    const float* __restrict__ x,
    const float* __restrict__ bd,
    const float* __restrict__ wenc,
    const float* __restrict__ benc,
    double* __restrict__ accs)
{
  __shared__ float xls[DM];                 // 8 KB
  __shared__ unsigned hist[256];
  __shared__ unsigned spool[CCAP];          // 3 KB
  __shared__ int   cidx[SORTN];
  __shared__ float cval[SORTN];
  __shared__ unsigned long long skey[SORTN];  // 2 KB
  __shared__ int   snc, snk;
  __shared__ float sthr;

  const int row  = blockIdx.x;
  const int tid  = threadIdx.x;
  const int lane = tid & 63;
  const int wid  = tid >> 6;
  const float* xr = x + (size_t)row * DM;
  unsigned cnt = rowcnt[row]; if (cnt > (unsigned)CCAP) cnt = CCAP;

  for (int i = tid; i < DM / 4; i += 256) {
    f32x4 xv = __builtin_nontemporal_load((const f32x4*)xr + i);
    f32x4 bv = ((const f32x4*)bd)[i];
    ((f32x4*)xls)[i] = xv - bv;
  }
  hist[tid] = 0;
  if (tid == 0) snc = 0;
  __syncthreads();

  f32x4 xreg[8];
#pragma unroll
  for (int t = 0; t < 8; ++t)
    xreg[t] = ((const f32x4*)xls)[t * 64 + lane];

  const unsigned* prow = poolc + (size_t)row * CCAP;
  for (int i = tid; i < (int)cnt; i += 256) {
    unsigned p = __builtin_nontemporal_load(prow + i);
    spool[i] = p;
    float v = __uint_as_float(p & 0xFFFF0000u);
    int b = (int)(v * 128.f); if (b > 255) b = 255;
    atomicAdd(&hist[b], 1u);
  }
  __syncthreads();
  if (tid == 0) {
    unsigned cum = 0; int b = 255; bool found = false;
    for (; b >= 128; --b) {
      cum += hist[b];
      if (cum >= (unsigned)KSEL) { found = true; break; }
    }
    // approx err <= gemm noise (7e-3) + bf16 pack (4e-3) = 0.011; margin 0.03
    sthr = found ? ((float)b * 0.0078125f - MARGIN) : 0.99f;
  }
  __syncthreads();
  const float thr = sthr;

  for (int i = tid; i < (int)cnt; i += 256) {
    unsigned p = spool[i];
    float v = __uint_as_float(p & 0xFFFF0000u);
    if (v > thr) { int q = atomicAdd(&snc, 1); if (q < SORTN) cidx[q] = (int)(p & 0xFFFFu); }
  }
  __syncthreads();
  const int NC = snc < SORTN ? snc : SORTN;

  // exact f32 rescore, one wave per candidate (chain identical to round 17)
  for (int c = wid; c < NC; c += 4) {
    const float* wr = wenc + (size_t)cidx[c] * DM;
    f32x4 p = {0.f, 0.f, 0.f, 0.f};
#pragma unroll
    for (int t = 0; t < 8; ++t) {
      f32x4 w4 = *(const f32x4*)(wr + t * 256 + lane * 4);
      p[0] = fmaf(xreg[t][0], w4[0], p[0]);
      p[1] = fmaf(xreg[t][1], w4[1], p[1]);
      p[2] = fmaf(xreg[t][2], w4[2], p[2]);
      p[3] = fmaf(xreg[t][3], w4[3], p[3]);
    }
    float s = (p[0] + p[1]) + (p[2] + p[3]);
#pragma unroll
    for (int off = 1; off < 64; off <<= 1)
      s += __shfl_xor(s, off);
    if (lane == 0) cval[c] = s + benc[cidx[c]];
  }
  __syncthreads();

  // keys: (valbits << 32) | (DD-1-idx)  — value desc, index asc (jax rule)
  {
    unsigned long long k = 0ULL;
    if (tid < NC) {
      float pv = cval[tid];
      if (pv > 0.f)
        k = ((unsigned long long)__float_as_uint(pv) << 32)
          | (unsigned)(DD - 1 - cidx[tid]);
    }
    skey[tid] = k;
  }
  __syncthreads();

  // bitonic sort, 256 keys descending (36 stages)
  for (int k = 2; k <= SORTN; k <<= 1) {
    for (int j = k >> 1; j > 0; j >>= 1) {
      int ixj = tid ^ j;
      if (ixj > tid) {
        unsigned long long a = skey[tid], b = skey[ixj];
        bool blockUp = (tid & k) == 0;     // descending overall
        if (blockUp ? (a < b) : (a > b)) { skey[tid] = b; skey[ixj] = a; }
      }
      __syncthreads();
    }
  }

  if (tid == 0) {
    int c = 0;
    for (int j = 0; j < KSEL; ++j) c += (skey[j] != 0ULL) ? 1 : 0;
    snk = c;
    atomicAdd(&accs[1], (double)c);
  }
  __syncthreads();
  const int nk = snk;

  if (tid < KSEL) {
    unsigned long long k = skey[tid];
    uint2 s;
    if (tid < nk) {
      s.x = (unsigned)((DD - 1) - (int)(k & 0xFFFFFFFFu));
      s.y = (unsigned)(k >> 32);
    } else {
      s.x = 0xFFFFFFFFu;
      s.y = 0u;
    }
    ((uint2*)(hbuf + (size_t)row * 16384))[tid] = s;
  }
}

// ---------------- finish: zero sel head, scatter, decode, metrics ----------
__global__ __launch_bounds__(256) void k_finish(
    float* __restrict__ h,
    const OutT* __restrict__ wdt,
    const float* __restrict__ x,
    const float* __restrict__ bd,
    float* __restrict__ xhat,
    double* __restrict__ accs)
{
  __shared__ int   sidx[KSEL];
  __shared__ float sval[KSEL];
  __shared__ float red[256];

  const int row = blockIdx.x;
  const int tid = threadIdx.x;
  float* hrow = h + (size_t)row * DD;

  if (tid < KSEL) {
    uint2 p = ((const uint2*)hrow)[tid];
    sidx[tid] = (int)p.x;
    sval[tid] = __uint_as_float(p.y);
  }
  __syncthreads();
  if (tid < KSEL) ((float2*)hrow)[tid] = make_float2(0.f, 0.f);
  __syncthreads();
  if (tid < KSEL && sidx[tid] >= 0) hrow[sidx[tid]] = sval[tid];

  const int d0 = tid * 8;
  f32x4 bv0 = ((const f32x4*)bd)[tid * 2];
  f32x4 bv1 = ((const f32x4*)bd)[tid * 2 + 1];
  float a0=bv0[0], a1=bv0[1], a2=bv0[2], a3=bv0[3];
  float a4=bv1[0], a5=bv1[1], a6=bv1[2], a7=bv1[3];
  for (int j = 0; j < KSEL; ++j) {
    if (sidx[j] < 0) continue;
    const float vv = sval[j];
    const uint4 w = *(const uint4*)(wdt + (size_t)sidx[j] * DM + d0);
    a0 = fmaf(vv, __uint_as_float(w.x << 16), a0);
    a1 = fmaf(vv, __uint_as_float(w.x & 0xFFFF0000u), a1);
    a2 = fmaf(vv, __uint_as_float(w.y << 16), a2);
    a3 = fmaf(vv, __uint_as_float(w.y & 0xFFFF0000u), a3);
    a4 = fmaf(vv, __uint_as_float(w.z << 16), a4);
    a5 = fmaf(vv, __uint_as_float(w.z & 0xFFFF0000u), a5);
    a6 = fmaf(vv, __uint_as_float(w.w << 16), a6);
    a7 = fmaf(vv, __uint_as_float(w.w & 0xFFFF0000u), a7);
  }
  const float* xr = x + (size_t)row * DM + d0;
  f32x4 xv0 = __builtin_nontemporal_load((const f32x4*)xr);
  f32x4 xv1 = __builtin_nontemporal_load((const f32x4*)(xr + 4));
  float s = 0.f, d;
  d = a0 - xv0[0]; s += d*d; d = a1 - xv0[1]; s += d*d;
  d = a2 - xv0[2]; s += d*d; d = a3 - xv0[3]; s += d*d;
  d = a4 - xv1[0]; s += d*d; d = a5 - xv1[1]; s += d*d;
  d = a6 - xv1[2]; s += d*d; d = a7 - xv1[3]; s += d*d;
  f32x4 o0 = {a0, a1, a2, a3};
  f32x4 o1 = {a4, a5, a6, a7};
  float* xo = xhat + (size_t)row * DM + d0;
  __builtin_nontemporal_store(o0, (f32x4*)xo);
  __builtin_nontemporal_store(o1, (f32x4*)(xo + 4));

  red[tid] = s; __syncthreads();
  for (int off = 128; off > 0; off >>= 1) {
    if (tid < off) red[tid] += red[tid + off];
    __syncthreads();
  }
  if (tid == 0) atomicAdd(&accs[0], (double)red[0]);
}

__global__ void k_final(const double* __restrict__ colsum, const double* __restrict__ accs,
                        float* __restrict__ osc) {
  __shared__ double rd[256];
  double s = 0.0;
  for (int c = threadIdx.x; c < DM; c += 256) { double m = colsum[c]; s += m * m; }
  rd[threadIdx.x] = s; __syncthreads();
  for (int off = 128; off > 0; off >>= 1) {
    if ((int)threadIdx.x < off) rd[threadIdx.x] += rd[threadIdx.x + off];
    __syncthreads();
  }
  if (threadIdx.x == 0) {
    double res = accs[0];
    double tv  = accs[2] - rd[0] / (double)NROWS;
    osc[0] = (float)(res / ((double)NROWS * (double)DM));   // recon_loss
    osc[1] = (float)(accs[1] / (double)NROWS);              // l0
    osc[2] = (float)(1.0 - res / (tv + 1e-8));              // explained_var
  }
}

extern "C" void kernel_launch(void* const* d_in, const int* in_sizes, int n_in,
                              void* d_out, int out_size, void* d_ws, size_t ws_size,
                              hipStream_t stream) {
  (void)in_sizes; (void)n_in; (void)out_size; (void)ws_size;
  const float* x    = (const float*)d_in[0];
  const float* wenc = (const float*)d_in[1];
  const float* benc = (const float*)d_in[2];
  const float* wdec = (const float*)d_in[3];
  const float* bdec = (const float*)d_in[4];

  // Outputs FLOAT32: x_hat [8192][2048], h [8192][16384], 3 scalars.
  float* out  = (float*)d_out;
  float* xhat = out;
  float* hbuf = out + (size_t)NROWS * DM;
  float* osc  = out + (size_t)NROWS * DM + (size_t)NROWS * DD;

  // xhat slot multi-use: [0,32MiB) x_bf16 (consumed by k_gemm);
  //   [32MiB,+25.2MiB) poolc; then rowcnt. k_finish overwrites with x_hat.
  OutT*     xb      = (OutT*)d_out;
  unsigned* xs32    = (unsigned*)d_out;
  unsigned* poolc   = xs32 + (size_t)8 * 1024 * 1024;
  unsigned* rowcnt  = poolc + (size_t)NROWS * CCAP;

  // Workspace: web bf16 64 MiB @0; wdt bf16 @64Mi; stats @128Mi.
  char* w = (char*)d_ws;
  OutT*   web    = (OutT*)w;
  OutT*   wdt    = (OutT*)(w + 67108864);
  double* colsum = (double*)(w + 134217728);
  double* accs   = (double*)(w + 134217728 + 16384);

  k_init       <<<1 + NROWS / 256, 256, 0, stream>>>(colsum, rowcnt);
  k_convx_stats<<<NROWS / 128, 256, 0, stream>>>(x, bdec, xb, colsum, accs);
  k_conv_w     <<<(DD * DM) / (256 * 8), 256, 0, stream>>>(wenc, web);
  k_gemm       <<<(NROWS / 128) * (DD / 128), 256, 0, stream>>>(xb, web, benc, hbuf, poolc, rowcnt);
  k_select     <<<NROWS, 256, 0, stream>>>((unsigned*)hbuf, poolc, rowcnt, x, bdec, wenc, benc, accs);
  k_twdec      <<<dim3(DD / 32, DM / 32), 256, 0, stream>>>(wdec, wdt);
  k_finish     <<<NROWS, 256, 0, stream>>>(hbuf, wdt, x, bdec, xhat, accs);
  k_final      <<<1, 256, 0, stream>>>(colsum, accs, osc);
}

// Round 22
// 1554.488 us; speedup vs baseline: 1.1817x; 1.1817x over previous
//
#include <hip/hip_runtime.h>
#include <hip/hip_bf16.h>
#include <stdint.h>

#define AS1 __attribute__((address_space(1)))
#define AS3 __attribute__((address_space(3)))

using bf16x8 = __attribute__((ext_vector_type(8))) short;
using f32x4  = __attribute__((ext_vector_type(4))) float;
using f16x4  = __attribute__((ext_vector_type(4))) _Float16;
using f16x8  = __attribute__((ext_vector_type(8))) _Float16;

static constexpr int NROWS = 8192;   // N
static constexpr int DM    = 2048;   // d_model
static constexpr int DD    = 16384;  // d_dict
static constexpr int KSEL  = 64;
static constexpr int CCAP  = 768;    // compact pool cap/row
static constexpr int SLOTS = 24;     // LDS pool slots per row per col-block
static constexpr int SORTN = 256;    // bitonic width (cand mean 84, 19-sigma safe)
static constexpr int BCAP  = 64;     // exact-rescue band cap (mean ~2)
#define POOLTHR 1.0f
#define MARGIN  0.03f
#define DELTA   1.0e-3f

using OutT = unsigned short;  // bf16 bit pattern

__device__ __forceinline__ unsigned short f2bf(float f) {
  unsigned u = __float_as_uint(f);
  u += 0x7FFFu + ((u >> 16) & 1u);
  return (unsigned short)(u >> 16);
}
__device__ __forceinline__ void gload16(const void* g, void* l) {
  __builtin_amdgcn_global_load_lds((const AS1 void*)g, (AS3 void*)l, 16, 0, 0);
}

// ---------------- fused init ----------------
__global__ void k_init(double* __restrict__ colsum, unsigned* __restrict__ rowcnt) {
  if (blockIdx.x == 0) {
    for (int i = threadIdx.x; i < 2048 + 8; i += 256) colsum[i] = 0.0;
  } else {
    rowcnt[(blockIdx.x - 1) * 256 + threadIdx.x] = 0u;
  }
}

// ---------------- fused conv_x + colstats ----------------
__global__ void k_convx_stats(const float* __restrict__ x, const float* __restrict__ bd,
                              OutT* __restrict__ xb, double* __restrict__ colsum,
                              double* __restrict__ accs) {
  __shared__ double rd[256];
  const int b = blockIdx.x;
  const int c0 = threadIdx.x * 8;
  float4 bv0 = *(const float4*)(bd + c0);
  float4 bv1 = *(const float4*)(bd + c0 + 4);
  float s0=0,s1=0,s2=0,s3=0,s4=0,s5=0,s6=0,s7=0;
  double sq = 0.0;
  for (int r = 0; r < 128; ++r) {
    const size_t base = (size_t)(b * 128 + r) * DM + c0;
    float4 u = *(const float4*)(x + base);
    float4 v = *(const float4*)(x + base + 4);
    s0+=u.x; s1+=u.y; s2+=u.z; s3+=u.w; s4+=v.x; s5+=v.y; s6+=v.z; s7+=v.w;
    sq += (double)u.x*u.x + (double)u.y*u.y + (double)u.z*u.z + (double)u.w*u.w
        + (double)v.x*v.x + (double)v.y*v.y + (double)v.z*v.z + (double)v.w*v.w;
    unsigned o0 = f2bf(u.x - bv0.x), o1 = f2bf(u.y - bv0.y);
    unsigned o2 = f2bf(u.z - bv0.z), o3 = f2bf(u.w - bv0.w);
    unsigned o4 = f2bf(v.x - bv1.x), o5 = f2bf(v.y - bv1.y);
    unsigned o6 = f2bf(v.z - bv1.z), o7 = f2bf(v.w - bv1.w);
    uint4 p;
    p.x = o0 | (o1 << 16); p.y = o2 | (o3 << 16);
    p.z = o4 | (o5 << 16); p.w = o6 | (o7 << 16);
    *(uint4*)(xb + base) = p;
  }
  atomicAdd(&colsum[c0+0], (double)s0); atomicAdd(&colsum[c0+1], (double)s1);
  atomicAdd(&colsum[c0+2], (double)s2); atomicAdd(&colsum[c0+3], (double)s3);
  atomicAdd(&colsum[c0+4], (double)s4); atomicAdd(&colsum[c0+5], (double)s5);
  atomicAdd(&colsum[c0+6], (double)s6); atomicAdd(&colsum[c0+7], (double)s7);
  rd[threadIdx.x] = sq; __syncthreads();
  for (int off = 128; off > 0; off >>= 1) {
    if ((int)threadIdx.x < off) rd[threadIdx.x] += rd[threadIdx.x + off];
    __syncthreads();
  }
  if (threadIdx.x == 0) atomicAdd(&accs[2], rd[0]);
}

__global__ void k_conv_w(const float* __restrict__ src, OutT* __restrict__ dst) {
  size_t i = ((size_t)blockIdx.x * blockDim.x + threadIdx.x) * 8;
  float4 a = *(const float4*)(src + i);
  float4 b = *(const float4*)(src + i + 4);
  unsigned o0 = f2bf(a.x), o1 = f2bf(a.y), o2 = f2bf(a.z), o3 = f2bf(a.w);
  unsigned o4 = f2bf(b.x), o5 = f2bf(b.y), o6 = f2bf(b.z), o7 = f2bf(b.w);
  uint4 p;
  p.x = o0 | (o1 << 16); p.y = o2 | (o3 << 16);
  p.z = o4 | (o5 << 16); p.w = o6 | (o7 << 16);
  *(uint4*)(dst + i) = p;
}

// wenc f32 -> fp16 table (written into the dead web region after k_gemm)
__global__ void k_conv_h(const float* __restrict__ src, _Float16* __restrict__ dst) {
  size_t i = ((size_t)blockIdx.x * blockDim.x + threadIdx.x) * 8;
  float4 a = *(const float4*)(src + i);
  float4 b = *(const float4*)(src + i + 4);
  f16x8 o;
  o[0] = (_Float16)a.x; o[1] = (_Float16)a.y; o[2] = (_Float16)a.z; o[3] = (_Float16)a.w;
  o[4] = (_Float16)b.x; o[5] = (_Float16)b.y; o[6] = (_Float16)b.z; o[7] = (_Float16)b.w;
  *(f16x8*)(dst + i) = o;
}

// transpose W_dec (DM x DD, f32) -> wdt (DD x DM, bf16)
__global__ void k_twdec(const float* __restrict__ wd, OutT* __restrict__ wdt) {
  __shared__ float t[32][33];
  const int ct = blockIdx.x;
  const int rt = blockIdx.y;
  const int tid = threadIdx.x;
  const int r  = tid >> 3;
  const int c4 = (tid & 7) * 4;
  float4 v = *(const float4*)(wd + (size_t)(rt * 32 + r) * DD + ct * 32 + c4);
  t[r][c4 + 0] = v.x; t[r][c4 + 1] = v.y; t[r][c4 + 2] = v.z; t[r][c4 + 3] = v.w;
  __syncthreads();
  unsigned a = f2bf(t[c4 + 0][r]), b = f2bf(t[c4 + 1][r]);
  unsigned c = f2bf(t[c4 + 2][r]), d = f2bf(t[c4 + 3][r]);
  uint2 p; p.x = a | (b << 16); p.y = c | (d << 16);
  *(uint2*)(wdt + (size_t)(ct * 32 + r) * DM + rt * 32 + c4) = p;
}

// ---------------- bf16 MFMA GEMM (gload_lds, 16 KB arena, XCD bands) -------
__global__ __launch_bounds__(256, 2) void k_gemm(
    const OutT* __restrict__ A,
    const OutT* __restrict__ B,
    const float* __restrict__ bias,
    float* __restrict__ h,
    unsigned* __restrict__ poolc,
    unsigned* __restrict__ rowcnt)
{
  __shared__ __align__(16) unsigned smem[4096];   // 16 KB arena
  OutT* As = (OutT*)smem;
  OutT* Bs = (OutT*)smem + 4096;
  unsigned (*lpool)[SLOTS] = (unsigned(*)[SLOTS])smem;
  unsigned* lcnt  = smem + 128 * SLOTS;
  unsigned* lbase = smem + 128 * SLOTS + 128;

  const int bid = blockIdx.x;
  const int xcd = bid & 7;
  const int idx = bid >> 3;
  const int bn  = xcd * 16 + (idx & 15);
  const int bm  = idx >> 4;
  const int tid = threadIdx.x;
  const int lane = tid & 63;
  const int wv = tid >> 6;
  const int wm = wv >> 1, wn = wv & 1;

  const int c0 = wv * 2, c1 = wv * 2 + 1;
  const int sr0 = c0 * 16 + (lane >> 2);
  const int sr1 = c1 * 16 + (lane >> 2);
  const int sk  = (lane & 3) * 8;
  const OutT* gA0 = A + (size_t)(bm * 128 + sr0) * DM + sk;
  const OutT* gA1 = A + (size_t)(bm * 128 + sr1) * DM + sk;
  const OutT* gB0 = B + (size_t)(bn * 128 + sr0) * DM + sk;
  const OutT* gB1 = B + (size_t)(bn * 128 + sr1) * DM + sk;
  OutT* lA0 = &As[c0 * 512];
  OutT* lA1 = &As[c1 * 512];
  OutT* lB0 = &Bs[c0 * 512];
  OutT* lB1 = &Bs[c1 * 512];

  const int fr = lane & 15;
  const int kg = (lane >> 4) * 8;

  f32x4 acc[4][4] = {};

  for (int kt = 0; kt < DM / 32; ++kt) {
    gload16(gA0, lA0); gload16(gA1, lA1);
    gload16(gB0, lB0); gload16(gB1, lB1);
    gA0 += 32; gA1 += 32; gB0 += 32; gB1 += 32;
    __syncthreads();
    bf16x8 af[4], bfr[4];
#pragma unroll
    for (int m = 0; m < 4; ++m)
      af[m] = *(const bf16x8*)&As[(wm * 64 + m * 16 + fr) * 32 + kg];
#pragma unroll
    for (int n = 0; n < 4; ++n)
      bfr[n] = *(const bf16x8*)&Bs[(wn * 64 + n * 16 + fr) * 32 + kg];
#pragma unroll
    for (int m = 0; m < 4; ++m)
#pragma unroll
      for (int n = 0; n < 4; ++n)
        acc[m][n] = __builtin_amdgcn_mfma_f32_16x16x32_bf16(af[m], bfr[n], acc[m][n], 0, 0, 0);
    __syncthreads();
  }

  if (tid < 128) lcnt[tid] = 0;
  __syncthreads();
  const int r0 = (lane >> 4) * 4;
#pragma unroll
  for (int n = 0; n < 4; ++n) {
    const int col = bn * 128 + wn * 64 + n * 16 + fr;
    const float bv = bias[col];
#pragma unroll
    for (int m = 0; m < 4; ++m) {
      const int lr = wm * 64 + m * 16 + r0;
#pragma unroll
      for (int r = 0; r < 4; ++r) {
        float v = acc[m][n][r] + bv;
        if (v > POOLTHR) {
          unsigned pos = atomicAdd(&lcnt[lr + r], 1u);
          if (pos < (unsigned)SLOTS)
            lpool[lr + r][pos] = ((unsigned)f2bf(v) << 16) | (unsigned)col;
        }
      }
    }
  }
  __syncthreads();
  if (tid < 128) {
    unsigned c = lcnt[tid]; if (c > (unsigned)SLOTS) c = SLOTS;
    lcnt[tid] = c;
    lbase[tid] = c ? atomicAdd(&rowcnt[bm * 128 + tid], c) : 0u;
  }
  __syncthreads();
  for (int i = tid; i < 128 * SLOTS; i += 256) {
    const int lr = i / SLOTS;
    const int slot = i - lr * SLOTS;
    if (slot < (int)lcnt[lr]) {
      unsigned p = lbase[lr] + (unsigned)slot;
      if (p < (unsigned)CCAP)
        poolc[(size_t)(bm * 128 + lr) * CCAP + p] = lpool[lr][slot];
    }
  }
  const f32x4 z4 = {0.f, 0.f, 0.f, 0.f};
  for (int i = tid; i < 4096; i += 256) {
    const int lr = i >> 5, cc = i & 31;
    __builtin_nontemporal_store(z4,
        (f32x4*)(h + (size_t)(bm * 128 + lr) * DD + bn * 128) + cc);
  }
}

// ---------------- select: fp16 rescore -> bitonic -> exact rescue -> bitonic
__global__ __launch_bounds__(256) void k_select(
    unsigned* __restrict__ hbuf,
    const unsigned* __restrict__ poolc,
    const unsigned* __restrict__ rowcnt,
    const float* __restrict__ x,
    const float* __restrict__ bd,
    const float* __restrict__ wenc,      // f32 (exact rescue)
    const _Float16* __restrict__ wh,     // fp16 table (approx, half the bytes)
    const float* __restrict__ benc,
    double* __restrict__ accs)
{
  __shared__ float xls[DM];                 // 8 KB
  __shared__ unsigned hist[256];
  __shared__ unsigned spool[CCAP];
  __shared__ int   cidx[SORTN];
  __shared__ float cval[SORTN];
  __shared__ unsigned long long skey[SORTN];
  __shared__ int   bidx[BCAP];
  __shared__ int   snc, snk, sbc;
  __shared__ float sthr;

  const int row  = blockIdx.x;
  const int tid  = threadIdx.x;
  const int lane = tid & 63;
  const int wid  = tid >> 6;
  const float* xr = x + (size_t)row * DM;
  unsigned cnt = rowcnt[row]; if (cnt > (unsigned)CCAP) cnt = CCAP;

  for (int i = tid; i < DM / 4; i += 256) {
    f32x4 xv = __builtin_nontemporal_load((const f32x4*)xr + i);
    f32x4 bv = ((const f32x4*)bd)[i];
    ((f32x4*)xls)[i] = xv - bv;
  }
  hist[tid] = 0;
  if (tid == 0) { snc = 0; sbc = 0; }
  __syncthreads();

  f32x4 xreg[8];
#pragma unroll
  for (int t = 0; t < 8; ++t)
    xreg[t] = ((const f32x4*)xls)[t * 64 + lane];

  const unsigned* prow = poolc + (size_t)row * CCAP;
  for (int i = tid; i < (int)cnt; i += 256) {
    unsigned p = __builtin_nontemporal_load(prow + i);
    spool[i] = p;
    float v = __uint_as_float(p & 0xFFFF0000u);
    int b = (int)(v * 128.f); if (b > 255) b = 255;
    atomicAdd(&hist[b], 1u);
  }
  __syncthreads();
  if (tid == 0) {
    unsigned cum = 0; int b = 255; bool found = false;
    for (; b >= 128; --b) {
      cum += hist[b];
      if (cum >= (unsigned)KSEL) { found = true; break; }
    }
    // approx err <= gemm noise (7e-3) + bf16 pack (4e-3) = 0.011; margin 0.03
    sthr = found ? ((float)b * 0.0078125f - MARGIN) : 0.99f;
  }
  __syncthreads();
  const float thr = sthr;

  for (int i = tid; i < (int)cnt; i += 256) {
    unsigned p = spool[i];
    float v = __uint_as_float(p & 0xFFFF0000u);
    if (v > thr) { int q = atomicAdd(&snc, 1); if (q < SORTN) cidx[q] = (int)(p & 0xFFFFu); }
  }
  __syncthreads();
  const int NC = snc < SORTN ? snc : SORTN;

  // ---- approx rescore from fp16 table (half the gather bytes/lines) ----
  for (int c = wid; c < NC; c += 4) {
    const _Float16* wr = wh + (size_t)cidx[c] * DM;
    f32x4 p = {0.f, 0.f, 0.f, 0.f};
#pragma unroll
    for (int t = 0; t < 8; ++t) {
      f16x4 wq = *(const f16x4*)(wr + t * 256 + lane * 4);
      p[0] = fmaf(xreg[t][0], (float)wq[0], p[0]);
      p[1] = fmaf(xreg[t][1], (float)wq[1], p[1]);
      p[2] = fmaf(xreg[t][2], (float)wq[2], p[2]);
      p[3] = fmaf(xreg[t][3], (float)wq[3], p[3]);
    }
    float s = (p[0] + p[1]) + (p[2] + p[3]);
#pragma unroll
    for (int off = 1; off < 64; off <<= 1)
      s += __shfl_xor(s, off);
    if (lane == 0) cval[c] = s + benc[cidx[c]];
  }
  __syncthreads();

  // ---- bitonic #1 on approx keys -> v64a ----
  {
    unsigned long long k = 0ULL;
    if (tid < NC) {
      float pv = cval[tid];
      if (pv > 0.f)
        k = ((unsigned long long)__float_as_uint(pv) << 32)
          | (unsigned)(DD - 1 - cidx[tid]);
    }
    skey[tid] = k;
  }
  __syncthreads();
  for (int k = 2; k <= SORTN; k <<= 1) {
    for (int j = k >> 1; j > 0; j >>= 1) {
      int ixj = tid ^ j;
      if (ixj > tid) {
        unsigned long long a = skey[tid], b = skey[ixj];
        bool blockUp = (tid & k) == 0;
        if (blockUp ? (a < b) : (a > b)) { skey[tid] = b; skey[ixj] = a; }
      }
      __syncthreads();
    }
  }
  float v64a = 0.f;
  {
    unsigned long long kk = skey[KSEL - 1];
    if (kk != 0ULL) v64a = __uint_as_float((unsigned)(kk >> 32));
    else {
      // fewer than 64 positives: band around the smallest kept value
      for (int j = KSEL - 1; j >= 0; --j)
        if (skey[j] != 0ULL) { v64a = __uint_as_float((unsigned)(skey[j] >> 32)); break; }
    }
  }

  // ---- exact f32 rescue of the boundary band (chain identical to r17) ----
  for (int i = tid; i < NC; i += 256) {
    if (fabsf(cval[i] - v64a) <= DELTA) {
      int q = atomicAdd(&sbc, 1);
      if (q < BCAP) bidx[q] = i;
    }
  }
  __syncthreads();
  const int nb = sbc < BCAP ? sbc : BCAP;
  for (int b2 = wid; b2 < nb; b2 += 4) {
    const int c = bidx[b2];
    const float* wr = wenc + (size_t)cidx[c] * DM;
    f32x4 p = {0.f, 0.f, 0.f, 0.f};
#pragma unroll
    for (int t = 0; t < 8; ++t) {
      f32x4 w4 = *(const f32x4*)(wr + t * 256 + lane * 4);
      p[0] = fmaf(xreg[t][0], w4[0], p[0]);
      p[1] = fmaf(xreg[t][1], w4[1], p[1]);
      p[2] = fmaf(xreg[t][2], w4[2], p[2]);
      p[3] = fmaf(xreg[t][3], w4[3], p[3]);
    }
    float s = (p[0] + p[1]) + (p[2] + p[3]);
#pragma unroll
    for (int off = 1; off < 64; off <<= 1)
      s += __shfl_xor(s, off);
    if (lane == 0) cval[c] = s + benc[cidx[c]];
  }
  __syncthreads();

  // ---- bitonic #2 on mixed keys (boundary exact) ----
  {
    unsigned long long k = 0ULL;
    if (tid < NC) {
      float pv = cval[tid];
      if (pv > 0.f)
        k = ((unsigned long long)__float_as_uint(pv) << 32)
          | (unsigned)(DD - 1 - cidx[tid]);
    }
    skey[tid] = k;
  }
  __syncthreads();
  for (int k = 2; k <= SORTN; k <<= 1) {
    for (int j = k >> 1; j > 0; j >>= 1) {
      int ixj = tid ^ j;
      if (ixj > tid) {
        unsigned long long a = skey[tid], b = skey[ixj];
        bool blockUp = (tid & k) == 0;
        if (blockUp ? (a < b) : (a > b)) { skey[tid] = b; skey[ixj] = a; }
      }
      __syncthreads();
    }
  }

  if (tid == 0) {
    int c = 0;
    for (int j = 0; j < KSEL; ++j) c += (skey[j] != 0ULL) ? 1 : 0;
    snk = c;
    atomicAdd(&accs[1], (double)c);
  }
  __syncthreads();
  const int nk = snk;

  if (tid < KSEL) {
    unsigned long long k = skey[tid];
    uint2 s;
    if (tid < nk) {
      s.x = (unsigned)((DD - 1) - (int)(k & 0xFFFFFFFFu));
      s.y = (unsigned)(k >> 32);
    } else {
      s.x = 0xFFFFFFFFu;
      s.y = 0u;
    }
    ((uint2*)(hbuf + (size_t)row * 16384))[tid] = s;
  }
}

// ---------------- finish: zero sel head, scatter, decode, metrics ----------
__global__ __launch_bounds__(256) void k_finish(
    float* __restrict__ h,
    const OutT* __restrict__ wdt,
    const float* __restrict__ x,
    const float* __restrict__ bd,
    float* __restrict__ xhat,
    double* __restrict__ accs)
{
  __shared__ int   sidx[KSEL];
  __shared__ float sval[KSEL];
  __shared__ float red[256];

  const int row = blockIdx.x;
  const int tid = threadIdx.x;
  float* hrow = h + (size_t)row * DD;

  if (tid < KSEL) {
    uint2 p = ((const uint2*)hrow)[tid];
    sidx[tid] = (int)p.x;
    sval[tid] = __uint_as_float(p.y);
  }
  __syncthreads();
  if (tid < KSEL) ((float2*)hrow)[tid] = make_float2(0.f, 0.f);
  __syncthreads();
  if (tid < KSEL && sidx[tid] >= 0) hrow[sidx[tid]] = sval[tid];

  const int d0 = tid * 8;
  f32x4 bv0 = ((const f32x4*)bd)[tid * 2];
  f32x4 bv1 = ((const f32x4*)bd)[tid * 2 + 1];
  float a0=bv0[0], a1=bv0[1], a2=bv0[2], a3=bv0[3];
  float a4=bv1[0], a5=bv1[1], a6=bv1[2], a7=bv1[3];
  for (int j = 0; j < KSEL; ++j) {
    if (sidx[j] < 0) continue;
    const float vv = sval[j];
    const uint4 w = *(const uint4*)(wdt + (size_t)sidx[j] * DM + d0);
    a0 = fmaf(vv, __uint_as_float(w.x << 16), a0);
    a1 = fmaf(vv, __uint_as_float(w.x & 0xFFFF0000u), a1);
    a2 = fmaf(vv, __uint_as_float(w.y << 16), a2);
    a3 = fmaf(vv, __uint_as_float(w.y & 0xFFFF0000u), a3);
    a4 = fmaf(vv, __uint_as_float(w.z << 16), a4);
    a5 = fmaf(vv, __uint_as_float(w.z & 0xFFFF0000u), a5);
    a6 = fmaf(vv, __uint_as_float(w.w << 16), a6);
    a7 = fmaf(vv, __uint_as_float(w.w & 0xFFFF0000u), a7);
  }
  const float* xr = x + (size_t)row * DM + d0;
  f32x4 xv0 = __builtin_nontemporal_load((const f32x4*)xr);
  f32x4 xv1 = __builtin_nontemporal_load((const f32x4*)(xr + 4));
  float s = 0.f, d;
  d = a0 - xv0[0]; s += d*d; d = a1 - xv0[1]; s += d*d;
  d = a2 - xv0[2]; s += d*d; d = a3 - xv0[3]; s += d*d;
  d = a4 - xv1[0]; s += d*d; d = a5 - xv1[1]; s += d*d;
  d = a6 - xv1[2]; s += d*d; d = a7 - xv1[3]; s += d*d;
  f32x4 o0 = {a0, a1, a2, a3};
  f32x4 o1 = {a4, a5, a6, a7};
  float* xo = xhat + (size_t)row * DM + d0;
  __builtin_nontemporal_store(o0, (f32x4*)xo);
  __builtin_nontemporal_store(o1, (f32x4*)(xo + 4));

  red[tid] = s; __syncthreads();
  for (int off = 128; off > 0; off >>= 1) {
    if (tid < off) red[tid] += red[tid + off];
    __syncthreads();
  }
  if (tid == 0) atomicAdd(&accs[0], (double)red[0]);
}

__global__ void k_final(const double* __restrict__ colsum, const double* __restrict__ accs,
                        float* __restrict__ osc) {
  __shared__ double rd[256];
  double s = 0.0;
  for (int c = threadIdx.x; c < DM; c += 256) { double m = colsum[c]; s += m * m; }
  rd[threadIdx.x] = s; __syncthreads();
  for (int off = 128; off > 0; off >>= 1) {
    if ((int)threadIdx.x < off) rd[threadIdx.x] += rd[threadIdx.x + off];
    __syncthreads();
  }
  if (threadIdx.x == 0) {
    double res = accs[0];
    double tv  = accs[2] - rd[0] / (double)NROWS;
    osc[0] = (float)(res / ((double)NROWS * (double)DM));   // recon_loss
    osc[1] = (float)(accs[1] / (double)NROWS);              // l0
    osc[2] = (float)(1.0 - res / (tv + 1e-8));              // explained_var
  }
}

extern "C" void kernel_launch(void* const* d_in, const int* in_sizes, int n_in,
                              void* d_out, int out_size, void* d_ws, size_t ws_size,
                              hipStream_t stream) {
  (void)in_sizes; (void)n_in; (void)out_size; (void)ws_size;
  const float* x    = (const float*)d_in[0];
  const float* wenc = (const float*)d_in[1];
  const float* benc = (const float*)d_in[2];
  const float* wdec = (const float*)d_in[3];
  const float* bdec = (const float*)d_in[4];

  // Outputs FLOAT32: x_hat [8192][2048], h [8192][16384], 3 scalars.
  float* out  = (float*)d_out;
  float* xhat = out;
  float* hbuf = out + (size_t)NROWS * DM;
  float* osc  = out + (size_t)NROWS * DM + (size_t)NROWS * DD;

  // xhat slot multi-use: [0,32MiB) x_bf16 (consumed by k_gemm);
  //   [32MiB,+25.2MiB) poolc; then rowcnt. k_finish overwrites with x_hat.
  OutT*     xb      = (OutT*)d_out;
  unsigned* xs32    = (unsigned*)d_out;
  unsigned* poolc   = xs32 + (size_t)8 * 1024 * 1024;
  unsigned* rowcnt  = poolc + (size_t)NROWS * CCAP;

  // Workspace: web bf16 64 MiB @0 — dead after k_gemm, REUSED as fp16 wenc
  // table; wdt bf16 @64Mi; stats @128Mi.
  char* w = (char*)d_ws;
  OutT*      web    = (OutT*)w;
  _Float16*  wh     = (_Float16*)w;
  OutT*   wdt    = (OutT*)(w + 67108864);
  double* colsum = (double*)(w + 134217728);
  double* accs   = (double*)(w + 134217728 + 16384);

  k_init       <<<1 + NROWS / 256, 256, 0, stream>>>(colsum, rowcnt);
  k_convx_stats<<<NROWS / 128, 256, 0, stream>>>(x, bdec, xb, colsum, accs);
  k_conv_w     <<<(DD * DM) / (256 * 8), 256, 0, stream>>>(wenc, web);
  k_gemm       <<<(NROWS / 128) * (DD / 128), 256, 0, stream>>>(xb, web, benc, hbuf, poolc, rowcnt);
  k_conv_h     <<<(DD * DM) / (256 * 8), 256, 0, stream>>>(wenc, wh);   // web dead
  k_select     <<<NROWS, 256, 0, stream>>>((unsigned*)hbuf, poolc, rowcnt, x, bdec, wenc, wh, benc, accs);
  k_twdec      <<<dim3(DD / 32, DM / 32), 256, 0, stream>>>(wdec, wdt);
  k_finish     <<<NROWS, 256, 0, stream>>>(hbuf, wdt, x, bdec, xhat, accs);
  k_final      <<<1, 256, 0, stream>>>(colsum, accs, osc);
}

// Round 23
// 1543.414 us; speedup vs baseline: 1.1902x; 1.0072x over previous
//
#include <hip/hip_runtime.h>
#include <hip/hip_bf16.h>
#include <stdint.h>

#define AS1 __attribute__((address_space(1)))
#define AS3 __attribute__((address_space(3)))

using f32x4 = __attribute__((ext_vector_type(4))) float;
using f16x4 = __attribute__((ext_vector_type(4))) _Float16;
using f16x8 = __attribute__((ext_vector_type(8))) _Float16;

static constexpr int NROWS = 8192;   // N
static constexpr int DM    = 2048;   // d_model
static constexpr int DD    = 16384;  // d_dict
static constexpr int KSEL  = 64;
static constexpr int CCAP  = 768;    // compact pool cap/row
static constexpr int SLOTS = 24;     // LDS pool slots per row per col-block
static constexpr int SORTN = 256;    // bitonic width (cand mean 84, 19-sigma safe)
static constexpr int BCAP  = 64;     // exact-rescue band cap (mean ~2)
#define POOLTHR 1.0f
#define MARGIN  0.03f
#define DELTA   1.0e-3f

using OutT = unsigned short;  // bf16 bit pattern

__device__ __forceinline__ unsigned short f2bf(float f) {
  unsigned u = __float_as_uint(f);
  u += 0x7FFFu + ((u >> 16) & 1u);
  return (unsigned short)(u >> 16);
}
__device__ __forceinline__ void gload16(const void* g, void* l) {
  __builtin_amdgcn_global_load_lds((const AS1 void*)g, (AS3 void*)l, 16, 0, 0);
}

// ---------------- fused init ----------------
__global__ void k_init(double* __restrict__ colsum, unsigned* __restrict__ rowcnt) {
  if (blockIdx.x == 0) {
    for (int i = threadIdx.x; i < 2048 + 8; i += 256) colsum[i] = 0.0;
  } else {
    rowcnt[(blockIdx.x - 1) * 256 + threadIdx.x] = 0u;
  }
}

// ---------------- fused conv_x (fp16) + colstats ----------------
__global__ void k_convx_stats(const float* __restrict__ x, const float* __restrict__ bd,
                              _Float16* __restrict__ xh, double* __restrict__ colsum,
                              double* __restrict__ accs) {
  __shared__ double rd[256];
  const int b = blockIdx.x;
  const int c0 = threadIdx.x * 8;
  float4 bv0 = *(const float4*)(bd + c0);
  float4 bv1 = *(const float4*)(bd + c0 + 4);
  float s0=0,s1=0,s2=0,s3=0,s4=0,s5=0,s6=0,s7=0;
  double sq = 0.0;
  for (int r = 0; r < 128; ++r) {
    const size_t base = (size_t)(b * 128 + r) * DM + c0;
    float4 u = *(const float4*)(x + base);
    float4 v = *(const float4*)(x + base + 4);
    s0+=u.x; s1+=u.y; s2+=u.z; s3+=u.w; s4+=v.x; s5+=v.y; s6+=v.z; s7+=v.w;
    sq += (double)u.x*u.x + (double)u.y*u.y + (double)u.z*u.z + (double)u.w*u.w
        + (double)v.x*v.x + (double)v.y*v.y + (double)v.z*v.z + (double)v.w*v.w;
    f16x8 o;
    o[0] = (_Float16)(u.x - bv0.x); o[1] = (_Float16)(u.y - bv0.y);
    o[2] = (_Float16)(u.z - bv0.z); o[3] = (_Float16)(u.w - bv0.w);
    o[4] = (_Float16)(v.x - bv1.x); o[5] = (_Float16)(v.y - bv1.y);
    o[6] = (_Float16)(v.z - bv1.z); o[7] = (_Float16)(v.w - bv1.w);
    *(f16x8*)(xh + base) = o;
  }
  atomicAdd(&colsum[c0+0], (double)s0); atomicAdd(&colsum[c0+1], (double)s1);
  atomicAdd(&colsum[c0+2], (double)s2); atomicAdd(&colsum[c0+3], (double)s3);
  atomicAdd(&colsum[c0+4], (double)s4); atomicAdd(&colsum[c0+5], (double)s5);
  atomicAdd(&colsum[c0+6], (double)s6); atomicAdd(&colsum[c0+7], (double)s7);
  rd[threadIdx.x] = sq; __syncthreads();
  for (int off = 128; off > 0; off >>= 1) {
    if ((int)threadIdx.x < off) rd[threadIdx.x] += rd[threadIdx.x + off];
    __syncthreads();
  }
  if (threadIdx.x == 0) atomicAdd(&accs[2], rd[0]);
}

// wenc f32 -> fp16 table (shared by gemm AND select approx rescore)
__global__ void k_conv_wh(const float* __restrict__ src, _Float16* __restrict__ dst) {
  size_t i = ((size_t)blockIdx.x * blockDim.x + threadIdx.x) * 8;
  float4 a = *(const float4*)(src + i);
  float4 b = *(const float4*)(src + i + 4);
  f16x8 o;
  o[0] = (_Float16)a.x; o[1] = (_Float16)a.y; o[2] = (_Float16)a.z; o[3] = (_Float16)a.w;
  o[4] = (_Float16)b.x; o[5] = (_Float16)b.y; o[6] = (_Float16)b.z; o[7] = (_Float16)b.w;
  *(f16x8*)(dst + i) = o;
}

// transpose W_dec (DM x DD, f32) -> wdt (DD x DM, bf16)
__global__ void k_twdec(const float* __restrict__ wd, OutT* __restrict__ wdt) {
  __shared__ float t[32][33];
  const int ct = blockIdx.x;
  const int rt = blockIdx.y;
  const int tid = threadIdx.x;
  const int r  = tid >> 3;
  const int c4 = (tid & 7) * 4;
  float4 v = *(const float4*)(wd + (size_t)(rt * 32 + r) * DD + ct * 32 + c4);
  t[r][c4 + 0] = v.x; t[r][c4 + 1] = v.y; t[r][c4 + 2] = v.z; t[r][c4 + 3] = v.w;
  __syncthreads();
  unsigned a = f2bf(t[c4 + 0][r]), b = f2bf(t[c4 + 1][r]);
  unsigned c = f2bf(t[c4 + 2][r]), d = f2bf(t[c4 + 3][r]);
  uint2 p; p.x = a | (b << 16); p.y = c | (d << 16);
  *(uint2*)(wdt + (size_t)(ct * 32 + r) * DM + rt * 32 + c4) = p;
}

// ---------------- f16 MFMA GEMM (gload_lds, 16 KB arena, XCD bands) --------
__global__ __launch_bounds__(256, 2) void k_gemm(
    const _Float16* __restrict__ A,   // [NROWS][DM] fp16 (x - b_dec)
    const _Float16* __restrict__ B,   // [DD][DM] fp16 (W_enc)
    const float* __restrict__ bias,
    float* __restrict__ h,
    unsigned* __restrict__ poolc,
    unsigned* __restrict__ rowcnt)
{
  __shared__ __align__(16) unsigned smem[4096];   // 16 KB arena
  _Float16* As = (_Float16*)smem;                  // [0, 8 KB)
  _Float16* Bs = (_Float16*)smem + 4096;           // [8 KB, 16 KB)
  unsigned (*lpool)[SLOTS] = (unsigned(*)[SLOTS])smem;
  unsigned* lcnt  = smem + 128 * SLOTS;
  unsigned* lbase = smem + 128 * SLOTS + 128;

  const int bid = blockIdx.x;
  const int xcd = bid & 7;
  const int idx = bid >> 3;
  const int bn  = xcd * 16 + (idx & 15);
  const int bm  = idx >> 4;
  const int tid = threadIdx.x;
  const int lane = tid & 63;
  const int wv = tid >> 6;
  const int wm = wv >> 1, wn = wv & 1;

  const int c0 = wv * 2, c1 = wv * 2 + 1;
  const int sr0 = c0 * 16 + (lane >> 2);
  const int sr1 = c1 * 16 + (lane >> 2);
  const int sk  = (lane & 3) * 8;
  const _Float16* gA0 = A + (size_t)(bm * 128 + sr0) * DM + sk;
  const _Float16* gA1 = A + (size_t)(bm * 128 + sr1) * DM + sk;
  const _Float16* gB0 = B + (size_t)(bn * 128 + sr0) * DM + sk;
  const _Float16* gB1 = B + (size_t)(bn * 128 + sr1) * DM + sk;
  _Float16* lA0 = &As[c0 * 512];
  _Float16* lA1 = &As[c1 * 512];
  _Float16* lB0 = &Bs[c0 * 512];
  _Float16* lB1 = &Bs[c1 * 512];

  const int fr = lane & 15;
  const int kg = (lane >> 4) * 8;

  f32x4 acc[4][4] = {};

  for (int kt = 0; kt < DM / 32; ++kt) {
    gload16(gA0, lA0); gload16(gA1, lA1);
    gload16(gB0, lB0); gload16(gB1, lB1);
    gA0 += 32; gA1 += 32; gB0 += 32; gB1 += 32;
    __syncthreads();
    f16x8 af[4], bfr[4];
#pragma unroll
    for (int m = 0; m < 4; ++m)
      af[m] = *(const f16x8*)&As[(wm * 64 + m * 16 + fr) * 32 + kg];
#pragma unroll
    for (int n = 0; n < 4; ++n)
      bfr[n] = *(const f16x8*)&Bs[(wn * 64 + n * 16 + fr) * 32 + kg];
#pragma unroll
    for (int m = 0; m < 4; ++m)
#pragma unroll
      for (int n = 0; n < 4; ++n)
        acc[m][n] = __builtin_amdgcn_mfma_f32_16x16x32_f16(af[m], bfr[n], acc[m][n], 0, 0, 0);
    __syncthreads();
  }

  if (tid < 128) lcnt[tid] = 0;
  __syncthreads();
  const int r0 = (lane >> 4) * 4;   // C/D: col = lane&15, row = (lane>>4)*4 + reg
#pragma unroll
  for (int n = 0; n < 4; ++n) {
    const int col = bn * 128 + wn * 64 + n * 16 + fr;
    const float bv = bias[col];
#pragma unroll
    for (int m = 0; m < 4; ++m) {
      const int lr = wm * 64 + m * 16 + r0;
#pragma unroll
      for (int r = 0; r < 4; ++r) {
        float v = acc[m][n][r] + bv;
        if (v > POOLTHR) {
          unsigned pos = atomicAdd(&lcnt[lr + r], 1u);
          if (pos < (unsigned)SLOTS)
            lpool[lr + r][pos] = ((unsigned)f2bf(v) << 16) | (unsigned)col;
        }
      }
    }
  }
  __syncthreads();
  if (tid < 128) {
    unsigned c = lcnt[tid]; if (c > (unsigned)SLOTS) c = SLOTS;
    lcnt[tid] = c;
    lbase[tid] = c ? atomicAdd(&rowcnt[bm * 128 + tid], c) : 0u;
  }
  __syncthreads();
  for (int i = tid; i < 128 * SLOTS; i += 256) {
    const int lr = i / SLOTS;
    const int slot = i - lr * SLOTS;
    if (slot < (int)lcnt[lr]) {
      unsigned p = lbase[lr] + (unsigned)slot;
      if (p < (unsigned)CCAP)
        poolc[(size_t)(bm * 128 + lr) * CCAP + p] = lpool[lr][slot];
    }
  }
  const f32x4 z4 = {0.f, 0.f, 0.f, 0.f};
  for (int i = tid; i < 4096; i += 256) {
    const int lr = i >> 5, cc = i & 31;
    __builtin_nontemporal_store(z4,
        (f32x4*)(h + (size_t)(bm * 128 + lr) * DD + bn * 128) + cc);
  }
}

// ---------------- select: fp16 rescore -> bitonic -> exact rescue -> bitonic
__global__ __launch_bounds__(256) void k_select(
    unsigned* __restrict__ hbuf,
    const unsigned* __restrict__ poolc,
    const unsigned* __restrict__ rowcnt,
    const float* __restrict__ x,
    const float* __restrict__ bd,
    const float* __restrict__ wenc,      // f32 (exact rescue)
    const _Float16* __restrict__ wh,     // fp16 table (approx)
    const float* __restrict__ benc,
    double* __restrict__ accs)
{
  __shared__ float xls[DM];                 // 8 KB
  __shared__ unsigned hist[256];
  __shared__ unsigned spool[CCAP];
  __shared__ int   cidx[SORTN];
  __shared__ float cval[SORTN];
  __shared__ unsigned long long skey[SORTN];
  __shared__ int   bidx[BCAP];
  __shared__ int   snc, snk, sbc;
  __shared__ float sthr;

  const int row  = blockIdx.x;
  const int tid  = threadIdx.x;
  const int lane = tid & 63;
  const int wid  = tid >> 6;
  const float* xr = x + (size_t)row * DM;
  unsigned cnt = rowcnt[row]; if (cnt > (unsigned)CCAP) cnt = CCAP;

  for (int i = tid; i < DM / 4; i += 256) {
    f32x4 xv = __builtin_nontemporal_load((const f32x4*)xr + i);
    f32x4 bv = ((const f32x4*)bd)[i];
    ((f32x4*)xls)[i] = xv - bv;
  }
  hist[tid] = 0;
  if (tid == 0) { snc = 0; sbc = 0; }
  __syncthreads();

  f32x4 xreg[8];
#pragma unroll
  for (int t = 0; t < 8; ++t)
    xreg[t] = ((const f32x4*)xls)[t * 64 + lane];

  const unsigned* prow = poolc + (size_t)row * CCAP;
  for (int i = tid; i < (int)cnt; i += 256) {
    unsigned p = __builtin_nontemporal_load(prow + i);
    spool[i] = p;
    float v = __uint_as_float(p & 0xFFFF0000u);
    int b = (int)(v * 128.f); if (b > 255) b = 255;
    atomicAdd(&hist[b], 1u);
  }
  __syncthreads();
  if (tid == 0) {
    unsigned cum = 0; int b = 255; bool found = false;
    for (; b >= 128; --b) {
      cum += hist[b];
      if (cum >= (unsigned)KSEL) { found = true; break; }
    }
    // approx err: fp16 gemm noise (~1e-3) + bf16 pack (4e-3) << margin 0.03
    sthr = found ? ((float)b * 0.0078125f - MARGIN) : 0.99f;
  }
  __syncthreads();
  const float thr = sthr;

  for (int i = tid; i < (int)cnt; i += 256) {
    unsigned p = spool[i];
    float v = __uint_as_float(p & 0xFFFF0000u);
    if (v > thr) { int q = atomicAdd(&snc, 1); if (q < SORTN) cidx[q] = (int)(p & 0xFFFFu); }
  }
  __syncthreads();
  const int NC = snc < SORTN ? snc : SORTN;

  // ---- approx rescore from fp16 table ----
  for (int c = wid; c < NC; c += 4) {
    const _Float16* wr = wh + (size_t)cidx[c] * DM;
    f32x4 p = {0.f, 0.f, 0.f, 0.f};
#pragma unroll
    for (int t = 0; t < 8; ++t) {
      f16x4 wq = *(const f16x4*)(wr + t * 256 + lane * 4);
      p[0] = fmaf(xreg[t][0], (float)wq[0], p[0]);
      p[1] = fmaf(xreg[t][1], (float)wq[1], p[1]);
      p[2] = fmaf(xreg[t][2], (float)wq[2], p[2]);
      p[3] = fmaf(xreg[t][3], (float)wq[3], p[3]);
    }
    float s = (p[0] + p[1]) + (p[2] + p[3]);
#pragma unroll
    for (int off = 1; off < 64; off <<= 1)
      s += __shfl_xor(s, off);
    if (lane == 0) cval[c] = s + benc[cidx[c]];
  }
  __syncthreads();

  // ---- bitonic #1 on approx keys -> v64a ----
  {
    unsigned long long k = 0ULL;
    if (tid < NC) {
      float pv = cval[tid];
      if (pv > 0.f)
        k = ((unsigned long long)__float_as_uint(pv) << 32)
          | (unsigned)(DD - 1 - cidx[tid]);
    }
    skey[tid] = k;
  }
  __syncthreads();
  for (int k = 2; k <= SORTN; k <<= 1) {
    for (int j = k >> 1; j > 0; j >>= 1) {
      int ixj = tid ^ j;
      if (ixj > tid) {
        unsigned long long a = skey[tid], b = skey[ixj];
        bool blockUp = (tid & k) == 0;
        if (blockUp ? (a < b) : (a > b)) { skey[tid] = b; skey[ixj] = a; }
      }
      __syncthreads();
    }
  }
  float v64a = 0.f;
  {
    unsigned long long kk = skey[KSEL - 1];
    if (kk != 0ULL) v64a = __uint_as_float((unsigned)(kk >> 32));
    else {
      for (int j = KSEL - 1; j >= 0; --j)
        if (skey[j] != 0ULL) { v64a = __uint_as_float((unsigned)(skey[j] >> 32)); break; }
    }
  }

  // ---- exact f32 rescue of the boundary band ----
  for (int i = tid; i < NC; i += 256) {
    if (fabsf(cval[i] - v64a) <= DELTA) {
      int q = atomicAdd(&sbc, 1);
      if (q < BCAP) bidx[q] = i;
    }
  }
  __syncthreads();
  const int nb = sbc < BCAP ? sbc : BCAP;
  for (int b2 = wid; b2 < nb; b2 += 4) {
    const int c = bidx[b2];
    const float* wr = wenc + (size_t)cidx[c] * DM;
    f32x4 p = {0.f, 0.f, 0.f, 0.f};
#pragma unroll
    for (int t = 0; t < 8; ++t) {
      f32x4 w4 = *(const f32x4*)(wr + t * 256 + lane * 4);
      p[0] = fmaf(xreg[t][0], w4[0], p[0]);
      p[1] = fmaf(xreg[t][1], w4[1], p[1]);
      p[2] = fmaf(xreg[t][2], w4[2], p[2]);
      p[3] = fmaf(xreg[t][3], w4[3], p[3]);
    }
    float s = (p[0] + p[1]) + (p[2] + p[3]);
#pragma unroll
    for (int off = 1; off < 64; off <<= 1)
      s += __shfl_xor(s, off);
    if (lane == 0) cval[c] = s + benc[cidx[c]];
  }
  __syncthreads();

  // ---- bitonic #2 on mixed keys (boundary exact) ----
  {
    unsigned long long k = 0ULL;
    if (tid < NC) {
      float pv = cval[tid];
      if (pv > 0.f)
        k = ((unsigned long long)__float_as_uint(pv) << 32)
          | (unsigned)(DD - 1 - cidx[tid]);
    }
    skey[tid] = k;
  }
  __syncthreads();
  for (int k = 2; k <= SORTN; k <<= 1) {
    for (int j = k >> 1; j > 0; j >>= 1) {
      int ixj = tid ^ j;
      if (ixj > tid) {
        unsigned long long a = skey[tid], b = skey[ixj];
        bool blockUp = (tid & k) == 0;
        if (blockUp ? (a < b) : (a > b)) { skey[tid] = b; skey[ixj] = a; }
      }
      __syncthreads();
    }
  }

  if (tid == 0) {
    int c = 0;
    for (int j = 0; j < KSEL; ++j) c += (skey[j] != 0ULL) ? 1 : 0;
    snk = c;
    atomicAdd(&accs[1], (double)c);
  }
  __syncthreads();
  const int nk = snk;

  if (tid < KSEL) {
    unsigned long long k = skey[tid];
    uint2 s;
    if (tid < nk) {
      s.x = (unsigned)((DD - 1) - (int)(k & 0xFFFFFFFFu));
      s.y = (unsigned)(k >> 32);
    } else {
      s.x = 0xFFFFFFFFu;
      s.y = 0u;
    }
    ((uint2*)(hbuf + (size_t)row * 16384))[tid] = s;
  }
}

// ---------------- finish: zero sel head, scatter, decode, metrics ----------
__global__ __launch_bounds__(256) void k_finish(
    float* __restrict__ h,
    const OutT* __restrict__ wdt,
    const float* __restrict__ x,
    const float* __restrict__ bd,
    float* __restrict__ xhat,
    double* __restrict__ accs)
{
  __shared__ int   sidx[KSEL];
  __shared__ float sval[KSEL];
  __shared__ float red[256];

  const int row = blockIdx.x;
  const int tid = threadIdx.x;
  float* hrow = h + (size_t)row * DD;

  if (tid < KSEL) {
    uint2 p = ((const uint2*)hrow)[tid];
    sidx[tid] = (int)p.x;
    sval[tid] = __uint_as_float(p.y);
  }
  __syncthreads();
  if (tid < KSEL) ((float2*)hrow)[tid] = make_float2(0.f, 0.f);
  __syncthreads();
  if (tid < KSEL && sidx[tid] >= 0) hrow[sidx[tid]] = sval[tid];

  const int d0 = tid * 8;
  f32x4 bv0 = ((const f32x4*)bd)[tid * 2];
  f32x4 bv1 = ((const f32x4*)bd)[tid * 2 + 1];
  float a0=bv0[0], a1=bv0[1], a2=bv0[2], a3=bv0[3];
  float a4=bv1[0], a5=bv1[1], a6=bv1[2], a7=bv1[3];
  for (int j = 0; j < KSEL; ++j) {
    if (sidx[j] < 0) continue;
    const float vv = sval[j];
    const uint4 w = *(const uint4*)(wdt + (size_t)sidx[j] * DM + d0);
    a0 = fmaf(vv, __uint_as_float(w.x << 16), a0);
    a1 = fmaf(vv, __uint_as_float(w.x & 0xFFFF0000u), a1);
    a2 = fmaf(vv, __uint_as_float(w.y << 16), a2);
    a3 = fmaf(vv, __uint_as_float(w.y & 0xFFFF0000u), a3);
    a4 = fmaf(vv, __uint_as_float(w.z << 16), a4);
    a5 = fmaf(vv, __uint_as_float(w.z & 0xFFFF0000u), a5);
    a6 = fmaf(vv, __uint_as_float(w.w << 16), a6);
    a7 = fmaf(vv, __uint_as_float(w.w & 0xFFFF0000u), a7);
  }
  const float* xr = x + (size_t)row * DM + d0;
  f32x4 xv0 = __builtin_nontemporal_load((const f32x4*)xr);
  f32x4 xv1 = __builtin_nontemporal_load((const f32x4*)(xr + 4));
  float s = 0.f, d;
  d = a0 - xv0[0]; s += d*d; d = a1 - xv0[1]; s += d*d;
  d = a2 - xv0[2]; s += d*d; d = a3 - xv0[3]; s += d*d;
  d = a4 - xv1[0]; s += d*d; d = a5 - xv1[1]; s += d*d;
  d = a6 - xv1[2]; s += d*d; d = a7 - xv1[3]; s += d*d;
  f32x4 o0 = {a0, a1, a2, a3};
  f32x4 o1 = {a4, a5, a6, a7};
  float* xo = xhat + (size_t)row * DM + d0;
  __builtin_nontemporal_store(o0, (f32x4*)xo);
  __builtin_nontemporal_store(o1, (f32x4*)(xo + 4));

  red[tid] = s; __syncthreads();
  for (int off = 128; off > 0; off >>= 1) {
    if (tid < off) red[tid] += red[tid + off];
    __syncthreads();
  }
  if (tid == 0) atomicAdd(&accs[0], (double)red[0]);
}

__global__ void k_final(const double* __restrict__ colsum, const double* __restrict__ accs,
                        float* __restrict__ osc) {
  __shared__ double rd[256];
  double s = 0.0;
  for (int c = threadIdx.x; c < DM; c += 256) { double m = colsum[c]; s += m * m; }
  rd[threadIdx.x] = s; __syncthreads();
  for (int off = 128; off > 0; off >>= 1) {
    if ((int)threadIdx.x < off) rd[threadIdx.x] += rd[threadIdx.x + off];
    __syncthreads();
  }
  if (threadIdx.x == 0) {
    double res = accs[0];
    double tv  = accs[2] - rd[0] / (double)NROWS;
    osc[0] = (float)(res / ((double)NROWS * (double)DM));   // recon_loss
    osc[1] = (float)(accs[1] / (double)NROWS);              // l0
    osc[2] = (float)(1.0 - res / (tv + 1e-8));              // explained_var
  }
}

extern "C" void kernel_launch(void* const* d_in, const int* in_sizes, int n_in,
                              void* d_out, int out_size, void* d_ws, size_t ws_size,
                              hipStream_t stream) {
  (void)in_sizes; (void)n_in; (void)out_size; (void)ws_size;
  const float* x    = (const float*)d_in[0];
  const float* wenc = (const float*)d_in[1];
  const float* benc = (const float*)d_in[2];
  const float* wdec = (const float*)d_in[3];
  const float* bdec = (const float*)d_in[4];

  // Outputs FLOAT32: x_hat [8192][2048], h [8192][16384], 3 scalars.
  float* out  = (float*)d_out;
  float* xhat = out;
  float* hbuf = out + (size_t)NROWS * DM;
  float* osc  = out + (size_t)NROWS * DM + (size_t)NROWS * DD;

  // xhat slot multi-use: [0,32MiB) x_fp16 (consumed by k_gemm);
  //   [32MiB,+25.2MiB) poolc; then rowcnt. k_finish overwrites with x_hat.
  _Float16* xh      = (_Float16*)d_out;
  unsigned* xs32    = (unsigned*)d_out;
  unsigned* poolc   = xs32 + (size_t)8 * 1024 * 1024;
  unsigned* rowcnt  = poolc + (size_t)NROWS * CCAP;

  // Workspace: wh fp16 64 MiB @0 (gemm + select); wdt bf16 @64Mi; stats @128Mi.
  char* w = (char*)d_ws;
  _Float16* wh   = (_Float16*)w;
  OutT*   wdt    = (OutT*)(w + 67108864);
  double* colsum = (double*)(w + 134217728);
  double* accs   = (double*)(w + 134217728 + 16384);

  k_init       <<<1 + NROWS / 256, 256, 0, stream>>>(colsum, rowcnt);
  k_convx_stats<<<NROWS / 128, 256, 0, stream>>>(x, bdec, xh, colsum, accs);
  k_conv_wh    <<<(DD * DM) / (256 * 8), 256, 0, stream>>>(wenc, wh);
  k_gemm       <<<(NROWS / 128) * (DD / 128), 256, 0, stream>>>(xh, wh, benc, hbuf, poolc, rowcnt);
  k_select     <<<NROWS, 256, 0, stream>>>((unsigned*)hbuf, poolc, rowcnt, x, bdec, wenc, wh, benc, accs);
  k_twdec      <<<dim3(DD / 32, DM / 32), 256, 0, stream>>>(wdec, wdt);
  k_finish     <<<NROWS, 256, 0, stream>>>(hbuf, wdt, x, bdec, xhat, accs);
  k_final      <<<1, 256, 0, stream>>>(colsum, accs, osc);
}